// Round 2
// baseline (10.915 us; speedup 1.0000x reference)
//
#include <hip/hip_runtime.h>

// UniGSA_layer: algebraic identity.
//   s = -inf where H==0; softmax mass lies entirely on H==1 entries;
//   coef[n,h] = sum_e H[n,e]*a[n,h,e] = sum of ALL nonzero softmax entries = 1.
//   => rst = fs * coef = fs  => output == feat, exactly (in exact arithmetic).
// Kernel is a pure copy of feat (10000 x 256 f32 = 10.24 MB).
//
// Round-2 micro-tune: grid-stride with 4x float4 per thread per iter
// (625 blocks instead of 2500 -> less CP dispatch work, 4 independent
// in-flight loads per lane for ILP). Copy itself is ~3 us at achievable BW;
// remainder of dur_us is graph-launch overhead.

__global__ __launch_bounds__(256, 8)
void UniGSA_copy_kernel(const float4* __restrict__ in,
                        float4* __restrict__ out,
                        int n4) {
    int i = (blockIdx.x * blockDim.x + threadIdx.x) * 4;
    int stride = gridDim.x * blockDim.x * 4;
    for (; i + 3 < n4; i += stride) {
        float4 a = in[i + 0];
        float4 b = in[i + 1];
        float4 c = in[i + 2];
        float4 d = in[i + 3];
        out[i + 0] = a;
        out[i + 1] = b;
        out[i + 2] = c;
        out[i + 3] = d;
    }
    // tail (n4 % 4) — none for this shape (640000 % 4 == 0), defensive:
    if (i < n4) {
        for (; i < n4; ++i) out[i] = in[i];
    }
}

extern "C" void kernel_launch(void* const* d_in, const int* in_sizes, int n_in,
                              void* d_out, int out_size, void* d_ws, size_t ws_size,
                              hipStream_t stream) {
    const float4* feat = (const float4*)d_in[0];
    float4* out = (float4*)d_out;

    // out_size = 2,560,000 floats = 640,000 float4 = 160,000 thread-iters.
    int n4 = out_size / 4;                    // float4 count
    int block = 256;
    int grid = (n4 / 4 + block - 1) / block;  // 625 blocks, one iter each
    UniGSA_copy_kernel<<<grid, block, 0, stream>>>(feat, out, n4);

    // Scalar tail if out_size % 16 != 0 (empty for this shape).
    int tail = out_size - n4 * 4;
    if (tail > 0) {
        hipMemcpyAsync((char*)d_out + (size_t)n4 * 16,
                       (const char*)d_in[0] + (size_t)n4 * 16,
                       (size_t)tail * sizeof(float),
                       hipMemcpyDeviceToDevice, stream);
    }
}